// Round 6
// baseline (448.282 us; speedup 1.0000x reference)
//
#include <hip/hip_runtime.h>

// Problem constants (from reference setup_inputs)
#define BATCH 16
#define CIN   3
#define H     384
#define W     384
#define HW    (H * W)
#define HO    382
#define WO    382
#define OFFC  18    // offset channels = 2*K
#define OOUT  3     // dcn output channels
#define KTAPS 9

// 1 px/thread. No LDS: all weights are wave-uniform with compile-time
// indices -> compiler emits batched s_load into SGPRs (scalar cache),
// keeping the VALU and LDS pipes free. Gathers are batched: all 36 corner
// indices + bilinear weights computed first, then 36 independent loads in
// flight per channel (3 epochs) instead of ~9 serialized per-tap epochs.
__global__ __launch_bounds__(256, 4)
void deform_mlp_kernel(const float* __restrict__ x,
                       const float* __restrict__ conv_w,
                       const float* __restrict__ conv_b,
                       const float* __restrict__ dcn_w,
                       const float* __restrict__ dcn_b,
                       float* __restrict__ out)
{
    const int total = BATCH * HO * WO;
    const int gid = blockIdx.x * 256 + threadIdx.x;
    if (gid >= total) return;

    const int wo  = gid % WO;
    const int tmp = gid / WO;
    const int ho  = tmp % HO;
    const int b   = tmp / HO;

    const float* xb = x + b * (CIN * HW);

    // 3x3x3 input patch (always in-bounds for VALID conv).
    float xp[CIN][3][3];
    #pragma unroll
    for (int c = 0; c < CIN; ++c) {
        const float* xc = xb + c * HW + ho * W + wo;
        #pragma unroll
        for (int i = 0; i < 3; ++i)
            #pragma unroll
            for (int j = 0; j < 3; ++j)
                xp[c][i][j] = xc[i * W + j];
    }

    // Offset conv: 18 channels, weights via scalar loads (uniform).
    float off[OFFC];
    #pragma unroll
    for (int o = 0; o < OFFC; ++o) {
        float a = conv_b[o];
        #pragma unroll
        for (int c = 0; c < CIN; ++c)
            #pragma unroll
            for (int i = 0; i < 3; ++i)
                #pragma unroll
                for (int j = 0; j < 3; ++j)
                    a = fmaf(conv_w[o * 27 + c * 9 + i * 3 + j], xp[c][i][j], a);
        off[o] = a;
    }

    // Phase 1: all 36 corner indices + bilinear weights (pure VALU).
    int   ix[KTAPS][4];
    float w4[KTAPS][4];
    #pragma unroll
    for (int k = 0; k < KTAPS; ++k) {
        const int ky = k / 3;
        const int kx = k % 3;
        const float py = off[2 * k]     + (float)(ho + ky);
        const float px = off[2 * k + 1] + (float)(wo + kx);
        const float y0f = floorf(py);
        const float x0f = floorf(px);
        const float wy = py - y0f;
        const float wx = px - x0f;
        const int y0 = (int)y0f;
        const int x0 = (int)x0f;
        const int y1 = y0 + 1;
        const int x1 = x0 + 1;

        const bool vy0 = (unsigned)y0 < (unsigned)H;
        const bool vy1 = (unsigned)y1 < (unsigned)H;
        const bool vx0 = (unsigned)x0 < (unsigned)W;
        const bool vx1 = (unsigned)x1 < (unsigned)W;

        const int cy0 = min(max(y0, 0), H - 1);
        const int cy1 = min(max(y1, 0), H - 1);
        const int cx0 = min(max(x0, 0), W - 1);
        const int cx1 = min(max(x1, 0), W - 1);

        w4[k][0] = (vy0 && vx0) ? (1.f - wy) * (1.f - wx) : 0.f;
        w4[k][1] = (vy0 && vx1) ? (1.f - wy) * wx         : 0.f;
        w4[k][2] = (vy1 && vx0) ? wy * (1.f - wx)         : 0.f;
        w4[k][3] = (vy1 && vx1) ? wy * wx                 : 0.f;

        ix[k][0] = cy0 * W + cx0;
        ix[k][1] = cy0 * W + cx1;
        ix[k][2] = cy1 * W + cx0;
        ix[k][3] = cy1 * W + cx1;
    }

    float acc0 = dcn_b[0];
    float acc1 = dcn_b[1];
    float acc2 = dcn_b[2];

    // Phase 2: channel-blocked gathers — 36 independent loads per epoch.
    #pragma unroll
    for (int c = 0; c < CIN; ++c) {
        const float* xc = xb + c * HW;
        float v[KTAPS][4];
        #pragma unroll
        for (int k = 0; k < KTAPS; ++k) {
            v[k][0] = xc[ix[k][0]];
            v[k][1] = xc[ix[k][1]];
            v[k][2] = xc[ix[k][2]];
            v[k][3] = xc[ix[k][3]];
        }
        #pragma unroll
        for (int k = 0; k < KTAPS; ++k) {
            float s = v[k][0] * w4[k][0];
            s = fmaf(v[k][1], w4[k][1], s);
            s = fmaf(v[k][2], w4[k][2], s);
            s = fmaf(v[k][3], w4[k][3], s);
            acc0 = fmaf(dcn_w[0 * 27 + c * 9 + k], s, acc0);
            acc1 = fmaf(dcn_w[1 * 27 + c * 9 + k], s, acc1);
            acc2 = fmaf(dcn_w[2 * 27 + c * 9 + k], s, acc2);
        }
    }

    const int obase = b * (OOUT * HO * WO) + ho * WO + wo;
    __builtin_nontemporal_store(acc0, out + obase);
    __builtin_nontemporal_store(acc1, out + obase + HO * WO);
    __builtin_nontemporal_store(acc2, out + obase + 2 * HO * WO);
}

extern "C" void kernel_launch(void* const* d_in, const int* in_sizes, int n_in,
                              void* d_out, int out_size, void* d_ws, size_t ws_size,
                              hipStream_t stream) {
    const float* x      = (const float*)d_in[0];
    const float* conv_w = (const float*)d_in[1];
    const float* conv_b = (const float*)d_in[2];
    const float* dcn_w  = (const float*)d_in[3];
    const float* dcn_b  = (const float*)d_in[4];
    float* out = (float*)d_out;

    const int total = BATCH * HO * WO;
    const int blocks = (total + 255) / 256;
    deform_mlp_kernel<<<blocks, 256, 0, stream>>>(x, conv_w, conv_b, dcn_w, dcn_b, out);
}

// Round 7
// 161.118 us; speedup vs baseline: 2.7823x; 2.7823x over previous
//
#include <hip/hip_runtime.h>

// Problem constants (from reference setup_inputs)
#define BATCH 16
#define CIN   3
#define H     384
#define W     384
#define HW    (H * W)
#define HO    382
#define WO    382
#define OFFC  18
#define OOUT  3
#define KTAPS 9

// 12-byte HWC pixel, 4-byte aligned (compiler emits global_load_dwordx3).
struct F3 { float a, b, c; };

// ---------------------------------------------------------------------------
// Pass 1: CHW -> HWC transpose of x into workspace (28.3 MB).
// Reads: 3 coalesced planes. Writes: 12 B/lane contiguous dwordx3.
__global__ __launch_bounds__(256)
void chw_to_hwc_kernel(const float* __restrict__ x, float* __restrict__ xt)
{
    const int gid = blockIdx.x * 256 + threadIdx.x;
    if (gid >= BATCH * HW) return;
    const int b = gid / HW;
    const int p = gid - b * HW;
    const float* xb = x + (size_t)b * (CIN * HW);
    F3 v;
    v.a = xb[p];
    v.b = xb[HW + p];
    v.c = xb[2 * HW + p];
    *(F3*)(xt + (size_t)gid * 3) = v;
}

// ---------------------------------------------------------------------------
// Pass 2: fused offset-conv + deformable gather, reading HWC x.
// Per-tap immediate consumption (no big arrays -> no spills, ~R2 reg shape).
// Weights via wave-uniform global derefs with compile-time indices -> s_load.
__global__ __launch_bounds__(256)
void deform_hwc_kernel(const float* __restrict__ xt,
                       const float* __restrict__ conv_w,
                       const float* __restrict__ conv_b,
                       const float* __restrict__ dcn_w,
                       const float* __restrict__ dcn_b,
                       float* __restrict__ out)
{
    const int total = BATCH * HO * WO;
    const int gid = blockIdx.x * 256 + threadIdx.x;
    if (gid >= total) return;

    const int wo  = gid % WO;
    const int tmp = gid / WO;
    const int ho  = tmp % HO;
    const int b   = tmp / HO;

    const float* xtb = xt + (size_t)b * (HW * 3);

    // 3x3 patch of HWC pixels (9 dwordx3 loads, always in-bounds for VALID).
    F3 xp[3][3];
    #pragma unroll
    for (int i = 0; i < 3; ++i)
        #pragma unroll
        for (int j = 0; j < 3; ++j)
            xp[i][j] = *(const F3*)(xtb + (size_t)((ho + i) * W + (wo + j)) * 3);

    // Offset conv: 18 channels, scalar weights.
    float off[OFFC];
    #pragma unroll
    for (int o = 0; o < OFFC; ++o) {
        float a = conv_b[o];
        #pragma unroll
        for (int i = 0; i < 3; ++i)
            #pragma unroll
            for (int j = 0; j < 3; ++j) {
                a = fmaf(conv_w[o * 27 + 0 * 9 + i * 3 + j], xp[i][j].a, a);
                a = fmaf(conv_w[o * 27 + 1 * 9 + i * 3 + j], xp[i][j].b, a);
                a = fmaf(conv_w[o * 27 + 2 * 9 + i * 3 + j], xp[i][j].c, a);
            }
        off[o] = a;
    }

    float acc0 = dcn_b[0];
    float acc1 = dcn_b[1];
    float acc2 = dcn_b[2];

    #pragma unroll
    for (int k = 0; k < KTAPS; ++k) {
        const int ky = k / 3;
        const int kx = k % 3;
        const float py = off[2 * k]     + (float)(ho + ky);
        const float px = off[2 * k + 1] + (float)(wo + kx);
        const float y0f = floorf(py);
        const float x0f = floorf(px);
        const float wy = py - y0f;
        const float wx = px - x0f;
        const int y0 = (int)y0f;
        const int x0 = (int)x0f;
        const int y1 = y0 + 1;
        const int x1 = x0 + 1;

        const bool vy0 = (unsigned)y0 < (unsigned)H;
        const bool vy1 = (unsigned)y1 < (unsigned)H;
        const bool vx0 = (unsigned)x0 < (unsigned)W;
        const bool vx1 = (unsigned)x1 < (unsigned)W;

        const int cy0 = min(max(y0, 0), H - 1);
        const int cy1 = min(max(y1, 0), H - 1);
        const int cx0 = min(max(x0, 0), W - 1);
        const int cx1 = min(max(x1, 0), W - 1);

        const float w00 = (vy0 && vx0) ? (1.f - wy) * (1.f - wx) : 0.f;
        const float w01 = (vy0 && vx1) ? (1.f - wy) * wx         : 0.f;
        const float w10 = (vy1 && vx0) ? wy * (1.f - wx)         : 0.f;
        const float w11 = (vy1 && vx1) ? wy * wx                 : 0.f;

        // One dwordx3 per corner: all 3 channels at once.
        const F3 v00 = *(const F3*)(xtb + (size_t)(cy0 * W + cx0) * 3);
        const F3 v01 = *(const F3*)(xtb + (size_t)(cy0 * W + cx1) * 3);
        const F3 v10 = *(const F3*)(xtb + (size_t)(cy1 * W + cx0) * 3);
        const F3 v11 = *(const F3*)(xtb + (size_t)(cy1 * W + cx1) * 3);

        float s0 = v00.a * w00; s0 = fmaf(v01.a, w01, s0); s0 = fmaf(v10.a, w10, s0); s0 = fmaf(v11.a, w11, s0);
        float s1 = v00.b * w00; s1 = fmaf(v01.b, w01, s1); s1 = fmaf(v10.b, w10, s1); s1 = fmaf(v11.b, w11, s1);
        float s2 = v00.c * w00; s2 = fmaf(v01.c, w01, s2); s2 = fmaf(v10.c, w10, s2); s2 = fmaf(v11.c, w11, s2);

        acc0 = fmaf(dcn_w[0 * 27 + 0 * 9 + k], s0, acc0);
        acc0 = fmaf(dcn_w[0 * 27 + 1 * 9 + k], s1, acc0);
        acc0 = fmaf(dcn_w[0 * 27 + 2 * 9 + k], s2, acc0);
        acc1 = fmaf(dcn_w[1 * 27 + 0 * 9 + k], s0, acc1);
        acc1 = fmaf(dcn_w[1 * 27 + 1 * 9 + k], s1, acc1);
        acc1 = fmaf(dcn_w[1 * 27 + 2 * 9 + k], s2, acc1);
        acc2 = fmaf(dcn_w[2 * 27 + 0 * 9 + k], s0, acc2);
        acc2 = fmaf(dcn_w[2 * 27 + 1 * 9 + k], s1, acc2);
        acc2 = fmaf(dcn_w[2 * 27 + 2 * 9 + k], s2, acc2);
    }

    const int obase = b * (OOUT * HO * WO) + ho * WO + wo;
    __builtin_nontemporal_store(acc0, out + obase);
    __builtin_nontemporal_store(acc1, out + obase + HO * WO);
    __builtin_nontemporal_store(acc2, out + obase + 2 * HO * WO);
}

// ---------------------------------------------------------------------------
// Fallback (ws too small): round-2 kernel, known-good at ~176 us.
__global__ __launch_bounds__(256)
void deform_fused_kernel(const float* __restrict__ x,
                         const float* __restrict__ conv_w,
                         const float* __restrict__ conv_b,
                         const float* __restrict__ dcn_w,
                         const float* __restrict__ dcn_b,
                         float* __restrict__ out)
{
    __shared__ float s_cw[OFFC * 27];
    __shared__ float s_cb[OFFC];
    __shared__ float s_dw[OOUT * 27];
    __shared__ float s_db[OOUT];

    const int t = threadIdx.x;
    for (int i = t; i < OFFC * 27; i += 256) s_cw[i] = conv_w[i];
    if (t < OFFC)      s_cb[t] = conv_b[t];
    if (t < OOUT * 27) s_dw[t] = dcn_w[t];
    if (t < OOUT)      s_db[t] = dcn_b[t];
    __syncthreads();

    const int total = BATCH * HO * WO;
    const int gid = blockIdx.x * 256 + t;
    if (gid >= total) return;

    const int wo  = gid % WO;
    const int tmp = gid / WO;
    const int ho  = tmp % HO;
    const int b   = tmp / HO;

    const float* xb = x + b * (CIN * HW);

    float xp[CIN][3][3];
    #pragma unroll
    for (int c = 0; c < CIN; ++c) {
        const float* xc = xb + c * HW + ho * W + wo;
        #pragma unroll
        for (int i = 0; i < 3; ++i)
            #pragma unroll
            for (int j = 0; j < 3; ++j)
                xp[c][i][j] = xc[i * W + j];
    }

    float off[OFFC];
    #pragma unroll
    for (int o = 0; o < OFFC; ++o) {
        float a = s_cb[o];
        const float* wv = &s_cw[o * 27];
        #pragma unroll
        for (int c = 0; c < CIN; ++c)
            #pragma unroll
            for (int i = 0; i < 3; ++i)
                #pragma unroll
                for (int j = 0; j < 3; ++j)
                    a = fmaf(wv[c * 9 + i * 3 + j], xp[c][i][j], a);
        off[o] = a;
    }

    float a0 = s_db[0], a1 = s_db[1], a2 = s_db[2];

    #pragma unroll
    for (int k = 0; k < KTAPS; ++k) {
        const int ky = k / 3;
        const int kx = k % 3;
        const float py = off[2 * k]     + (float)(ho + ky);
        const float px = off[2 * k + 1] + (float)(wo + kx);
        const float y0f = floorf(py);
        const float x0f = floorf(px);
        const float wy = py - y0f;
        const float wx = px - x0f;
        const int y0 = (int)y0f;
        const int x0 = (int)x0f;
        const int y1 = y0 + 1;
        const int x1 = x0 + 1;
        const bool vy0 = (unsigned)y0 < (unsigned)H;
        const bool vy1 = (unsigned)y1 < (unsigned)H;
        const bool vx0 = (unsigned)x0 < (unsigned)W;
        const bool vx1 = (unsigned)x1 < (unsigned)W;
        const int cy0 = min(max(y0, 0), H - 1);
        const int cy1 = min(max(y1, 0), H - 1);
        const int cx0 = min(max(x0, 0), W - 1);
        const int cx1 = min(max(x1, 0), W - 1);
        const float w00 = (vy0 && vx0) ? (1.f - wy) * (1.f - wx) : 0.f;
        const float w01 = (vy0 && vx1) ? (1.f - wy) * wx         : 0.f;
        const float w10 = (vy1 && vx0) ? wy * (1.f - wx)         : 0.f;
        const float w11 = (vy1 && vx1) ? wy * wx                 : 0.f;
        const int i00 = cy0 * W + cx0;
        const int i01 = cy0 * W + cx1;
        const int i10 = cy1 * W + cx0;
        const int i11 = cy1 * W + cx1;
        #pragma unroll
        for (int c = 0; c < CIN; ++c) {
            const float* xc = xb + c * HW;
            float s = xc[i00] * w00;
            s = fmaf(xc[i01], w01, s);
            s = fmaf(xc[i10], w10, s);
            s = fmaf(xc[i11], w11, s);
            a0 = fmaf(s_dw[0 * 27 + c * 9 + k], s, a0);
            a1 = fmaf(s_dw[1 * 27 + c * 9 + k], s, a1);
            a2 = fmaf(s_dw[2 * 27 + c * 9 + k], s, a2);
        }
    }

    const int obase = b * (OOUT * HO * WO) + ho * WO + wo;
    __builtin_nontemporal_store(a0, out + obase);
    __builtin_nontemporal_store(a1, out + obase + HO * WO);
    __builtin_nontemporal_store(a2, out + obase + 2 * HO * WO);
}

extern "C" void kernel_launch(void* const* d_in, const int* in_sizes, int n_in,
                              void* d_out, int out_size, void* d_ws, size_t ws_size,
                              hipStream_t stream) {
    const float* x      = (const float*)d_in[0];
    const float* conv_w = (const float*)d_in[1];
    const float* conv_b = (const float*)d_in[2];
    const float* dcn_w  = (const float*)d_in[3];
    const float* dcn_b  = (const float*)d_in[4];
    float* out = (float*)d_out;

    const int total = BATCH * HO * WO;
    const size_t need = (size_t)BATCH * HW * 3 * sizeof(float);   // 28.3 MB

    if (ws_size >= need) {
        float* xt = (float*)d_ws;
        chw_to_hwc_kernel<<<(BATCH * HW + 255) / 256, 256, 0, stream>>>(x, xt);
        deform_hwc_kernel<<<(total + 255) / 256, 256, 0, stream>>>(
            xt, conv_w, conv_b, dcn_w, dcn_b, out);
    } else {
        deform_fused_kernel<<<(total + 255) / 256, 256, 0, stream>>>(
            x, conv_w, conv_b, dcn_w, dcn_b, out);
    }
}

// Round 8
// 156.088 us; speedup vs baseline: 2.8720x; 1.0322x over previous
//
#include <hip/hip_runtime.h>

// Problem constants (from reference setup_inputs)
#define BATCH 16
#define CIN   3
#define H     384
#define W     384
#define HW    (H * W)
#define HO    382
#define WO    382
#define OFFC  18
#define OOUT  3
#define KTAPS 9

// Padded HWC-float4 layout: 2-px zero halo reproduces OOB-mask semantics.
#define PAD   2
#define HP    (H + 2 * PAD)     // 388
#define WP    (W + 2 * PAD)     // 388

struct F3 { float a, b, c; };

// ---------------------------------------------------------------------------
// Pass 1a: CHW -> padded HWC float4 (zero halo), 38.5 MB workspace.
__global__ __launch_bounds__(256)
void chw_to_hwc4_kernel(const float* __restrict__ x, float4* __restrict__ xt)
{
    const int gid = blockIdx.x * 256 + threadIdx.x;
    if (gid >= BATCH * HP * WP) return;
    const int b  = gid / (HP * WP);
    const int r2 = gid - b * (HP * WP);
    const int ry = r2 / WP;
    const int rx = r2 - ry * WP;
    const int yi = ry - PAD;
    const int xi = rx - PAD;
    float4 v = make_float4(0.f, 0.f, 0.f, 0.f);
    if ((unsigned)yi < (unsigned)H && (unsigned)xi < (unsigned)W) {
        const float* xb = x + (size_t)b * (CIN * HW);
        const int p = yi * W + xi;
        v.x = xb[p];
        v.y = xb[HW + p];
        v.z = xb[2 * HW + p];
    }
    xt[gid] = v;
}

// ---------------------------------------------------------------------------
// Pass 2a: fused offset-conv + deformable gather on padded float4 HWC.
// No masks (halo zeros), 2 addresses/tap (corner pairs contiguous),
// wave-uniform weights via scalar loads, per-tap immediate consumption.
__global__ __launch_bounds__(256)
void deform_pad4_kernel(const float4* __restrict__ xt,
                        const float* __restrict__ conv_w,
                        const float* __restrict__ conv_b,
                        const float* __restrict__ dcn_w,
                        const float* __restrict__ dcn_b,
                        float* __restrict__ out)
{
    const int total = BATCH * HO * WO;
    const int gid = blockIdx.x * 256 + threadIdx.x;
    if (gid >= total) return;

    const int wo  = gid % WO;
    const int tmp = gid / WO;
    const int ho  = tmp % HO;
    const int b   = tmp / HO;

    const float4* xtb = xt + (size_t)b * (HP * WP);

    // 3x3 patch (interior of padded frame; 3 bases, imm offsets 0/16/32).
    float4 xp[3][3];
    #pragma unroll
    for (int i = 0; i < 3; ++i) {
        const float4* row = xtb + (ho + i + PAD) * WP + (wo + PAD);
        xp[i][0] = row[0];
        xp[i][1] = row[1];
        xp[i][2] = row[2];
    }

    // Offset conv: 18 channels, scalar weights.
    float off[OFFC];
    #pragma unroll
    for (int o = 0; o < OFFC; ++o) {
        float a = conv_b[o];
        #pragma unroll
        for (int i = 0; i < 3; ++i)
            #pragma unroll
            for (int j = 0; j < 3; ++j) {
                a = fmaf(conv_w[o * 27 + 0 * 9 + i * 3 + j], xp[i][j].x, a);
                a = fmaf(conv_w[o * 27 + 1 * 9 + i * 3 + j], xp[i][j].y, a);
                a = fmaf(conv_w[o * 27 + 2 * 9 + i * 3 + j], xp[i][j].z, a);
            }
        off[o] = a;
    }

    float acc0 = dcn_b[0];
    float acc1 = dcn_b[1];
    float acc2 = dcn_b[2];

    #pragma unroll
    for (int k = 0; k < KTAPS; ++k) {
        const int ky = k / 3;
        const int kx = k % 3;
        const float oy = off[2 * k];
        const float ox = off[2 * k + 1];
        const float fy = floorf(oy);
        const float fx = floorf(ox);
        const float wy = oy - fy;
        const float wx = ox - fx;

        // Padded-frame corner (y0, x0); clamp into frame so (..+1) stays in.
        // Any clamped / out-of-image coordinate lands on halo zeros, which
        // reproduces the reference's validity masking exactly.
        int iy = (int)fy + (ho + ky + PAD);
        int ix = (int)fx + (wo + kx + PAD);
        iy = min(max(iy, 0), HP - 2);
        ix = min(max(ix, 0), WP - 2);

        const float4* r0 = xtb + iy * WP + ix;
        const float4* r1 = r0 + WP;
        const float4 v00 = r0[0];
        const float4 v01 = r0[1];
        const float4 v10 = r1[0];
        const float4 v11 = r1[1];

        const float cwy = 1.f - wy;
        const float cwx = 1.f - wx;
        const float w00 = cwy * cwx;
        const float w01 = cwy * wx;
        const float w10 = wy * cwx;
        const float w11 = wy * wx;

        float s0 = v00.x * w00; s0 = fmaf(v01.x, w01, s0); s0 = fmaf(v10.x, w10, s0); s0 = fmaf(v11.x, w11, s0);
        float s1 = v00.y * w00; s1 = fmaf(v01.y, w01, s1); s1 = fmaf(v10.y, w10, s1); s1 = fmaf(v11.y, w11, s1);
        float s2 = v00.z * w00; s2 = fmaf(v01.z, w01, s2); s2 = fmaf(v10.z, w10, s2); s2 = fmaf(v11.z, w11, s2);

        acc0 = fmaf(dcn_w[0 * 27 + 0 * 9 + k], s0, acc0);
        acc0 = fmaf(dcn_w[0 * 27 + 1 * 9 + k], s1, acc0);
        acc0 = fmaf(dcn_w[0 * 27 + 2 * 9 + k], s2, acc0);
        acc1 = fmaf(dcn_w[1 * 27 + 0 * 9 + k], s0, acc1);
        acc1 = fmaf(dcn_w[1 * 27 + 1 * 9 + k], s1, acc1);
        acc1 = fmaf(dcn_w[1 * 27 + 2 * 9 + k], s2, acc1);
        acc2 = fmaf(dcn_w[2 * 27 + 0 * 9 + k], s0, acc2);
        acc2 = fmaf(dcn_w[2 * 27 + 1 * 9 + k], s1, acc2);
        acc2 = fmaf(dcn_w[2 * 27 + 2 * 9 + k], s2, acc2);
    }

    const int obase = b * (OOUT * HO * WO) + ho * WO + wo;
    __builtin_nontemporal_store(acc0, out + obase);
    __builtin_nontemporal_store(acc1, out + obase + HO * WO);
    __builtin_nontemporal_store(acc2, out + obase + 2 * HO * WO);
}

// ---------------------------------------------------------------------------
// Fallback A (ws >= 28.3 MB): round-7 HWC float3 path (~101 us kernels).
__global__ __launch_bounds__(256)
void chw_to_hwc_kernel(const float* __restrict__ x, float* __restrict__ xt)
{
    const int gid = blockIdx.x * 256 + threadIdx.x;
    if (gid >= BATCH * HW) return;
    const int b = gid / HW;
    const int p = gid - b * HW;
    const float* xb = x + (size_t)b * (CIN * HW);
    F3 v;
    v.a = xb[p];
    v.b = xb[HW + p];
    v.c = xb[2 * HW + p];
    *(F3*)(xt + (size_t)gid * 3) = v;
}

__global__ __launch_bounds__(256)
void deform_hwc_kernel(const float* __restrict__ xt,
                       const float* __restrict__ conv_w,
                       const float* __restrict__ conv_b,
                       const float* __restrict__ dcn_w,
                       const float* __restrict__ dcn_b,
                       float* __restrict__ out)
{
    const int total = BATCH * HO * WO;
    const int gid = blockIdx.x * 256 + threadIdx.x;
    if (gid >= total) return;

    const int wo  = gid % WO;
    const int tmp = gid / WO;
    const int ho  = tmp % HO;
    const int b   = tmp / HO;

    const float* xtb = xt + (size_t)b * (HW * 3);

    F3 xp[3][3];
    #pragma unroll
    for (int i = 0; i < 3; ++i)
        #pragma unroll
        for (int j = 0; j < 3; ++j)
            xp[i][j] = *(const F3*)(xtb + (size_t)((ho + i) * W + (wo + j)) * 3);

    float off[OFFC];
    #pragma unroll
    for (int o = 0; o < OFFC; ++o) {
        float a = conv_b[o];
        #pragma unroll
        for (int i = 0; i < 3; ++i)
            #pragma unroll
            for (int j = 0; j < 3; ++j) {
                a = fmaf(conv_w[o * 27 + 0 * 9 + i * 3 + j], xp[i][j].a, a);
                a = fmaf(conv_w[o * 27 + 1 * 9 + i * 3 + j], xp[i][j].b, a);
                a = fmaf(conv_w[o * 27 + 2 * 9 + i * 3 + j], xp[i][j].c, a);
            }
        off[o] = a;
    }

    float acc0 = dcn_b[0];
    float acc1 = dcn_b[1];
    float acc2 = dcn_b[2];

    #pragma unroll
    for (int k = 0; k < KTAPS; ++k) {
        const int ky = k / 3;
        const int kx = k % 3;
        const float py = off[2 * k]     + (float)(ho + ky);
        const float px = off[2 * k + 1] + (float)(wo + kx);
        const float y0f = floorf(py);
        const float x0f = floorf(px);
        const float wy = py - y0f;
        const float wx = px - x0f;
        const int y0 = (int)y0f;
        const int x0 = (int)x0f;
        const int y1 = y0 + 1;
        const int x1 = x0 + 1;
        const bool vy0 = (unsigned)y0 < (unsigned)H;
        const bool vy1 = (unsigned)y1 < (unsigned)H;
        const bool vx0 = (unsigned)x0 < (unsigned)W;
        const bool vx1 = (unsigned)x1 < (unsigned)W;
        const int cy0 = min(max(y0, 0), H - 1);
        const int cy1 = min(max(y1, 0), H - 1);
        const int cx0 = min(max(x0, 0), W - 1);
        const int cx1 = min(max(x1, 0), W - 1);
        const float w00 = (vy0 && vx0) ? (1.f - wy) * (1.f - wx) : 0.f;
        const float w01 = (vy0 && vx1) ? (1.f - wy) * wx         : 0.f;
        const float w10 = (vy1 && vx0) ? wy * (1.f - wx)         : 0.f;
        const float w11 = (vy1 && vx1) ? wy * wx                 : 0.f;

        const F3 v00 = *(const F3*)(xtb + (size_t)(cy0 * W + cx0) * 3);
        const F3 v01 = *(const F3*)(xtb + (size_t)(cy0 * W + cx1) * 3);
        const F3 v10 = *(const F3*)(xtb + (size_t)(cy1 * W + cx0) * 3);
        const F3 v11 = *(const F3*)(xtb + (size_t)(cy1 * W + cx1) * 3);

        float s0 = v00.a * w00; s0 = fmaf(v01.a, w01, s0); s0 = fmaf(v10.a, w10, s0); s0 = fmaf(v11.a, w11, s0);
        float s1 = v00.b * w00; s1 = fmaf(v01.b, w01, s1); s1 = fmaf(v10.b, w10, s1); s1 = fmaf(v11.b, w11, s1);
        float s2 = v00.c * w00; s2 = fmaf(v01.c, w01, s2); s2 = fmaf(v10.c, w10, s2); s2 = fmaf(v11.c, w11, s2);

        acc0 = fmaf(dcn_w[0 * 27 + 0 * 9 + k], s0, acc0);
        acc0 = fmaf(dcn_w[0 * 27 + 1 * 9 + k], s1, acc0);
        acc0 = fmaf(dcn_w[0 * 27 + 2 * 9 + k], s2, acc0);
        acc1 = fmaf(dcn_w[1 * 27 + 0 * 9 + k], s0, acc1);
        acc1 = fmaf(dcn_w[1 * 27 + 1 * 9 + k], s1, acc1);
        acc1 = fmaf(dcn_w[1 * 27 + 2 * 9 + k], s2, acc1);
        acc2 = fmaf(dcn_w[2 * 27 + 0 * 9 + k], s0, acc2);
        acc2 = fmaf(dcn_w[2 * 27 + 1 * 9 + k], s1, acc2);
        acc2 = fmaf(dcn_w[2 * 27 + 2 * 9 + k], s2, acc2);
    }

    const int obase = b * (OOUT * HO * WO) + ho * WO + wo;
    __builtin_nontemporal_store(acc0, out + obase);
    __builtin_nontemporal_store(acc1, out + obase + HO * WO);
    __builtin_nontemporal_store(acc2, out + obase + 2 * HO * WO);
}

// ---------------------------------------------------------------------------
// Fallback B (tiny ws): round-2 fused kernel (~176 us), no workspace.
__global__ __launch_bounds__(256)
void deform_fused_kernel(const float* __restrict__ x,
                         const float* __restrict__ conv_w,
                         const float* __restrict__ conv_b,
                         const float* __restrict__ dcn_w,
                         const float* __restrict__ dcn_b,
                         float* __restrict__ out)
{
    __shared__ float s_cw[OFFC * 27];
    __shared__ float s_cb[OFFC];
    __shared__ float s_dw[OOUT * 27];
    __shared__ float s_db[OOUT];

    const int t = threadIdx.x;
    for (int i = t; i < OFFC * 27; i += 256) s_cw[i] = conv_w[i];
    if (t < OFFC)      s_cb[t] = conv_b[t];
    if (t < OOUT * 27) s_dw[t] = dcn_w[t];
    if (t < OOUT)      s_db[t] = dcn_b[t];
    __syncthreads();

    const int total = BATCH * HO * WO;
    const int gid = blockIdx.x * 256 + t;
    if (gid >= total) return;

    const int wo  = gid % WO;
    const int tmp = gid / WO;
    const int ho  = tmp % HO;
    const int b   = tmp / HO;

    const float* xb = x + b * (CIN * HW);

    float xp[CIN][3][3];
    #pragma unroll
    for (int c = 0; c < CIN; ++c) {
        const float* xc = xb + c * HW + ho * W + wo;
        #pragma unroll
        for (int i = 0; i < 3; ++i)
            #pragma unroll
            for (int j = 0; j < 3; ++j)
                xp[c][i][j] = xc[i * W + j];
    }

    float off[OFFC];
    #pragma unroll
    for (int o = 0; o < OFFC; ++o) {
        float a = s_cb[o];
        const float* wv = &s_cw[o * 27];
        #pragma unroll
        for (int c = 0; c < CIN; ++c)
            #pragma unroll
            for (int i = 0; i < 3; ++i)
                #pragma unroll
                for (int j = 0; j < 3; ++j)
                    a = fmaf(wv[c * 9 + i * 3 + j], xp[c][i][j], a);
        off[o] = a;
    }

    float a0 = s_db[0], a1 = s_db[1], a2 = s_db[2];

    #pragma unroll
    for (int k = 0; k < KTAPS; ++k) {
        const int ky = k / 3;
        const int kx = k % 3;
        const float py = off[2 * k]     + (float)(ho + ky);
        const float px = off[2 * k + 1] + (float)(wo + kx);
        const float y0f = floorf(py);
        const float x0f = floorf(px);
        const float wy = py - y0f;
        const float wx = px - x0f;
        const int y0 = (int)y0f;
        const int x0 = (int)x0f;
        const int y1 = y0 + 1;
        const int x1 = x0 + 1;
        const bool vy0 = (unsigned)y0 < (unsigned)H;
        const bool vy1 = (unsigned)y1 < (unsigned)H;
        const bool vx0 = (unsigned)x0 < (unsigned)W;
        const bool vx1 = (unsigned)x1 < (unsigned)W;
        const int cy0 = min(max(y0, 0), H - 1);
        const int cy1 = min(max(y1, 0), H - 1);
        const int cx0 = min(max(x0, 0), W - 1);
        const int cx1 = min(max(x1, 0), W - 1);
        const float w00 = (vy0 && vx0) ? (1.f - wy) * (1.f - wx) : 0.f;
        const float w01 = (vy0 && vx1) ? (1.f - wy) * wx         : 0.f;
        const float w10 = (vy1 && vx0) ? wy * (1.f - wx)         : 0.f;
        const float w11 = (vy1 && vx1) ? wy * wx                 : 0.f;
        const int i00 = cy0 * W + cx0;
        const int i01 = cy0 * W + cx1;
        const int i10 = cy1 * W + cx0;
        const int i11 = cy1 * W + cx1;
        #pragma unroll
        for (int c = 0; c < CIN; ++c) {
            const float* xc = xb + c * HW;
            float s = xc[i00] * w00;
            s = fmaf(xc[i01], w01, s);
            s = fmaf(xc[i10], w10, s);
            s = fmaf(xc[i11], w11, s);
            a0 = fmaf(s_dw[0 * 27 + c * 9 + k], s, a0);
            a1 = fmaf(s_dw[1 * 27 + c * 9 + k], s, a1);
            a2 = fmaf(s_dw[2 * 27 + c * 9 + k], s, a2);
        }
    }

    const int obase = b * (OOUT * HO * WO) + ho * WO + wo;
    __builtin_nontemporal_store(a0, out + obase);
    __builtin_nontemporal_store(a1, out + obase + HO * WO);
    __builtin_nontemporal_store(a2, out + obase + 2 * HO * WO);
}

extern "C" void kernel_launch(void* const* d_in, const int* in_sizes, int n_in,
                              void* d_out, int out_size, void* d_ws, size_t ws_size,
                              hipStream_t stream) {
    const float* x      = (const float*)d_in[0];
    const float* conv_w = (const float*)d_in[1];
    const float* conv_b = (const float*)d_in[2];
    const float* dcn_w  = (const float*)d_in[3];
    const float* dcn_b  = (const float*)d_in[4];
    float* out = (float*)d_out;

    const int total = BATCH * HO * WO;
    const size_t need4 = (size_t)BATCH * HP * WP * sizeof(float4);   // 38.5 MB
    const size_t need3 = (size_t)BATCH * HW * 3 * sizeof(float);     // 28.3 MB

    if (ws_size >= need4) {
        float4* xt = (float4*)d_ws;
        const int cells = BATCH * HP * WP;
        chw_to_hwc4_kernel<<<(cells + 255) / 256, 256, 0, stream>>>(x, xt);
        deform_pad4_kernel<<<(total + 255) / 256, 256, 0, stream>>>(
            xt, conv_w, conv_b, dcn_w, dcn_b, out);
    } else if (ws_size >= need3) {
        float* xt = (float*)d_ws;
        chw_to_hwc_kernel<<<(BATCH * HW + 255) / 256, 256, 0, stream>>>(x, xt);
        deform_hwc_kernel<<<(total + 255) / 256, 256, 0, stream>>>(
            xt, conv_w, conv_b, dcn_w, dcn_b, out);
    } else {
        deform_fused_kernel<<<(total + 255) / 256, 256, 0, stream>>>(
            x, conv_w, conv_b, dcn_w, dcn_b, out);
    }
}